// Round 1
// baseline (273.846 us; speedup 1.0000x reference)
//
#include <hip/hip_runtime.h>
#include <hip/hip_bf16.h>
#include <math.h>

// Problem constants
constexpr int Bn = 2, Ln = 128, Dn = 256, Hn = 256;

// log(expm1(0.01))
#define LR_SHIFT (-4.6001660040607144f)

// Workspace offsets (floats)
constexpr int OFF_Q      = 0;        // [B,L,D]
constexpr int OFF_K      = 65536;    // [B,L,D]
constexpr int OFF_V      = 131072;   // [B,L,D]
constexpr int OFF_X2     = 196608;   // [B,L,H]
constexpr int OFF_GZ1    = 262144;   // [B,L,H]
constexpr int OFF_GZ2    = 327680;   // [B,L,D]
constexpr int OFF_XQ     = 393216;   // [B,L,H]
constexpr int OFF_P1     = 458752;   // [B,L,L]
constexpr int OFF_P2     = 491520;   // [B,L,L]
constexpr int OFF_A      = 524288;   // [B,L,L]  A = Dm@M (lower-tri)
constexpr int OFF_W1T    = 557056;   // [B,D,H]  W1 transposed
constexpr int OFF_W2T    = 688128;   // [B,H,D]  W2 transposed
constexpr int OFF_MW1T   = 819200;   // [B,D,H]
constexpr int OFF_MW2T   = 950272;   // [B,H,D]
constexpr int OFF_LR     = 1081344;  // [B,L]
constexpr int OFF_PM     = 1081600;  // [B,L] prefix sum of log_mom (inclusive)
constexpr int OFF_PD     = 1081856;  // [B,L] prefix sum of log_wd
constexpr int OFF_MOMCUM = 1082112;  // [B,L]
constexpr int OFF_WDCUM  = 1082368;  // [B,L]
constexpr int OFF_C      = 1082624;  // [B,L]  c = Dm @ mom_cum
constexpr int OFF_LOGM   = 1082880;  // [B,L]
constexpr int OFF_LOGWD  = 1083136;  // [B,L]
// total 1083392 floats ~= 4.3 MB

// Output offsets (floats), tuple order
constexpr int OUT_ZQ2  = 0;       // [B,L,D]
constexpr int OUT_W1P  = 65536;   // [B,H,D]
constexpr int OUT_B1P  = 196608;  // [B,H]
constexpr int OUT_W2P  = 197120;  // [B,D,H]
constexpr int OUT_B2P  = 328192;  // [B,D]
constexpr int OUT_MGW1 = 328704;  // [B,H,D]
constexpr int OUT_MGB1 = 459776;  // [B,H]
constexpr int OUT_MGW2 = 460288;  // [B,D,H]
constexpr int OUT_MGB2 = 591360;  // [B,D]

__device__ __forceinline__ float softplus_f(float z) {
    return fmaxf(z, 0.0f) + log1pf(expf(-fabsf(z)));
}

// ---------------------------------------------------------------------------
// k0: transpose W1, W2, mW1, mW2 (each [256,256] per batch) into workspace
// ---------------------------------------------------------------------------
__global__ __launch_bounds__(256) void transpose_kernel(
    const float* __restrict__ W1, const float* __restrict__ W2,
    const float* __restrict__ mW1, const float* __restrict__ mW2,
    float* __restrict__ ws) {
    int z = blockIdx.z; int mat = z >> 1; int b = z & 1;
    const float* src; float* dst;
    if (mat == 0)      { src = W1  + b * 65536; dst = ws + OFF_W1T  + b * 65536; }
    else if (mat == 1) { src = W2  + b * 65536; dst = ws + OFF_W2T  + b * 65536; }
    else if (mat == 2) { src = mW1 + b * 65536; dst = ws + OFF_MW1T + b * 65536; }
    else               { src = mW2 + b * 65536; dst = ws + OFF_MW2T + b * 65536; }
    __shared__ float tile[32][33];
    int tx = threadIdx.x & 31, ty = threadIdx.x >> 5;
    int r0 = blockIdx.y * 32, c0 = blockIdx.x * 32;
    for (int i = 0; i < 32; i += 8)
        tile[ty + i][tx] = src[(r0 + ty + i) * 256 + (c0 + tx)];
    __syncthreads();
    for (int i = 0; i < 32; i += 8)
        dst[(c0 + ty + i) * 256 + (r0 + tx)] = tile[tx][ty + i];
}

// ---------------------------------------------------------------------------
// k1: Q/K/V projections + scalar projections (lr, log_mom, log_wd)
// one block per token (b,l); 256 threads
// ---------------------------------------------------------------------------
__global__ __launch_bounds__(256) void proj_kernel(
    const float* __restrict__ x,
    const float* __restrict__ Wq, const float* __restrict__ bq,
    const float* __restrict__ Wk, const float* __restrict__ bk,
    const float* __restrict__ Wv, const float* __restrict__ bv,
    const float* __restrict__ Wlr, const float* __restrict__ blr,
    const float* __restrict__ Wm, const float* __restrict__ bm,
    const float* __restrict__ Wd, const float* __restrict__ bd,
    float* __restrict__ ws) {
    int bl = blockIdx.x;             // b*L + l
    int t = threadIdx.x;
    __shared__ float xs[256];
    __shared__ float red[256];
    xs[t] = x[bl * 256 + t];
    __syncthreads();

    float q = bq[t], k = bk[t], v = bv[t];
#pragma unroll 4
    for (int d = 0; d < 256; ++d) {
        float xv = xs[d];
        q += xv * Wq[d * 256 + t];
        k += xv * Wk[d * 256 + t];
        v += xv * Wv[d * 256 + t];
    }
    ws[OFF_Q + bl * 256 + t] = q;
    ws[OFF_K + bl * 256 + t] = k;
    ws[OFF_V + bl * 256 + t] = v;

    // three dot-product reductions over D
    float fc_lr, fc_m, fc_d;
    red[t] = xs[t] * Wlr[t]; __syncthreads();
    for (int s = 128; s > 0; s >>= 1) { if (t < s) red[t] += red[t + s]; __syncthreads(); }
    fc_lr = red[0]; __syncthreads();
    red[t] = xs[t] * Wm[t]; __syncthreads();
    for (int s = 128; s > 0; s >>= 1) { if (t < s) red[t] += red[t + s]; __syncthreads(); }
    fc_m = red[0]; __syncthreads();
    red[t] = xs[t] * Wd[t]; __syncthreads();
    for (int s = 128; s > 0; s >>= 1) { if (t < s) red[t] += red[t + s]; __syncthreads(); }
    fc_d = red[0];

    if (t == 0) {
        ws[OFF_LR + bl]    = softplus_f(fc_lr + blr[0] + LR_SHIFT);
        ws[OFF_LOGM + bl]  = -softplus_f(-(fc_m + bm[0]));
        ws[OFF_LOGWD + bl] = -softplus_f(fc_d + bd[0]);
    }
}

// ---------------------------------------------------------------------------
// k2: per-batch prefix scans -> Pm, Pd, mom_cum, wd_cum, c
// one block per batch, 128 threads
// ---------------------------------------------------------------------------
__global__ __launch_bounds__(128) void scan_kernel(float* __restrict__ ws) {
    int b = blockIdx.x; int t = threadIdx.x;
    __shared__ float sm[128], sd[128], se[128];
    sm[t] = ws[OFF_LOGM + b * Ln + t];
    sd[t] = ws[OFF_LOGWD + b * Ln + t];
    __syncthreads();
    for (int off = 1; off < 128; off <<= 1) {
        float am = (t >= off) ? sm[t - off] : 0.0f;
        float ad = (t >= off) ? sd[t - off] : 0.0f;
        __syncthreads();
        sm[t] += am; sd[t] += ad;
        __syncthreads();
    }
    float pm = sm[t], pd = sd[t];
    ws[OFF_PM + b * Ln + t] = pm;
    ws[OFF_PD + b * Ln + t] = pd;
    ws[OFF_MOMCUM + b * Ln + t] = expf(pm);
    ws[OFF_WDCUM + b * Ln + t]  = expf(pd);
    // c[l] = sum_{m<=l} Dm[l,m]*mom_cum[m] = exp(Pd[l]) * sum_{m<=l} exp(Pm[m]-Pd[m])
    se[t] = expf(pm - pd);
    __syncthreads();
    for (int off = 1; off < 128; off <<= 1) {
        float a = (t >= off) ? se[t - off] : 0.0f;
        __syncthreads();
        se[t] += a;
        __syncthreads();
    }
    ws[OFF_C + b * Ln + t] = expf(pd) * se[t];
}

// ---------------------------------------------------------------------------
// k3: A = Dm @ M  (lower-tri, per batch). one block per (b,l), 128 threads (m')
// A[l,m'] = sum_{m=m'..l} exp(Pd[l]-Pd[m]) * exp(Pm[m]-Pm[m'])
// ---------------------------------------------------------------------------
__global__ __launch_bounds__(128) void a_kernel(float* __restrict__ ws) {
    int bl = blockIdx.x; int b = bl >> 7; int l = bl & 127;
    int m1 = threadIdx.x;
    const float* Pm = ws + OFF_PM + b * Ln;
    const float* Pd = ws + OFF_PD + b * Ln;
    float a = 0.0f;
    if (m1 <= l) {
        float pdl = Pd[l], pmm1 = Pm[m1];
        float s = 0.0f;
        for (int m = m1; m <= l; ++m)
            s += expf((pdl - Pd[m]) + (Pm[m] - pmm1));
        a = s;
    }
    ws[OFF_A + bl * Ln + m1] = a;
}

// ---------------------------------------------------------------------------
// k4: forward MLP + per-token grads: X2, gZ2, gZ1. one block per token.
// ---------------------------------------------------------------------------
__global__ __launch_bounds__(256) void fwd_kernel(
    const float* __restrict__ W2, const float* __restrict__ b1,
    const float* __restrict__ b2, float* __restrict__ ws) {
    int bl = blockIdx.x; int b = bl >> 7;
    int t = threadIdx.x;
    __shared__ float ks[256], x2s[256], gz2s[256];
    const float* W1t = ws + OFF_W1T + b * 65536;
    const float* W2t = ws + OFF_W2T + b * 65536;
    ks[t] = ws[OFF_K + bl * 256 + t];
    __syncthreads();
    // Z1[h=t] = b1[h] + sum_d W1[h,d]*k[d]  (W1t[d*H+h] coalesced)
    float z1 = b1[b * 256 + t];
#pragma unroll 4
    for (int d = 0; d < 256; ++d) z1 += ks[d] * W1t[d * 256 + t];
    float sg = 1.0f / (1.0f + expf(-z1));
    float x2 = z1 * sg;
    ws[OFF_X2 + bl * 256 + t] = x2;
    x2s[t] = x2;
    __syncthreads();
    // Z2[d=t] = b2[d] + sum_h W2[d,h]*x2[h]  (W2t[h*D+d] coalesced)
    float z2 = b2[b * 256 + t];
#pragma unroll 4
    for (int h = 0; h < 256; ++h) z2 += x2s[h] * W2t[h * 256 + t];
    float gz2 = z2 - ws[OFF_V + bl * 256 + t];
    ws[OFF_GZ2 + bl * 256 + t] = gz2;
    gz2s[t] = gz2;
    __syncthreads();
    // gX2[h=t] = sum_d gz2[d]*W2[d,h]  (original W2 layout coalesced over h)
    const float* W2b = W2 + b * 65536;
    float gx2 = 0.0f;
#pragma unroll 4
    for (int d = 0; d < 256; ++d) gx2 += gz2s[d] * W2b[d * 256 + t];
    // silu_backward(z1) = silu + sigmoid*(1-silu)
    float gz1 = gx2 * (x2 + sg * (1.0f - x2));
    ws[OFF_GZ1 + bl * 256 + t] = gz1;
}

// ---------------------------------------------------------------------------
// k5/k7: P[l,m] = A[l,m]*lr[m]*(1 + qrow[l]·krow[m]) for m<=l, else 0
// one block per (b,l), 128 threads (m)
// ---------------------------------------------------------------------------
__global__ __launch_bounds__(128) void score_kernel(
    const float* __restrict__ qrows, const float* __restrict__ krows,
    float* __restrict__ pout, const float* __restrict__ ws) {
    int bl = blockIdx.x; int b = bl >> 7; int l = bl & 127;
    int m = threadIdx.x;
    __shared__ float qs[256];
    qs[m] = qrows[bl * 256 + m];
    qs[m + 128] = qrows[bl * 256 + m + 128];
    __syncthreads();
    float p = 0.0f;
    if (m <= l) {
        const float* kr = krows + (b * Ln + m) * 256;
        float s = 0.0f;
#pragma unroll 4
        for (int d = 0; d < 256; ++d) s += kr[d] * qs[d];
        p = ws[OFF_A + bl * Ln + m] * ws[OFF_LR + b * Ln + m] * (s + 1.0f);
    }
    pout[bl * Ln + m] = p;
}

// ---------------------------------------------------------------------------
// k6: Zq1 + silu -> Xq. one block per token, 256 threads (h)
// Zq1[l,h] = sum_{m<=l} P1[l,m]*gZ1[m,h] - c[l]*(mW1 q + mb1)[h] + wd[l]*(W1 q + b1)[h]
// ---------------------------------------------------------------------------
__global__ __launch_bounds__(256) void zq1_kernel(
    const float* __restrict__ b1, const float* __restrict__ mb1,
    float* __restrict__ ws) {
    int bl = blockIdx.x; int b = bl >> 7; int l = bl & 127;
    int h = threadIdx.x;
    __shared__ float qs[256];
    __shared__ float ps[128];
    qs[h] = ws[OFF_Q + bl * 256 + h];
    if (h < 128) ps[h] = ws[OFF_P1 + bl * Ln + h];
    __syncthreads();
    float acc = 0.0f;
    for (int m = 0; m <= l; ++m)
        acc += ps[m] * ws[OFF_GZ1 + (b * Ln + m) * 256 + h];
    const float* W1t  = ws + OFF_W1T  + b * 65536;
    const float* mW1t = ws + OFF_MW1T + b * 65536;
    float u = 0.0f, v = 0.0f;
#pragma unroll 4
    for (int d = 0; d < 256; ++d) {
        float qd = qs[d];
        u += qd * W1t[d * 256 + h];
        v += qd * mW1t[d * 256 + h];
    }
    float cl = ws[OFF_C + b * Ln + l];
    float wd = ws[OFF_WDCUM + b * Ln + l];
    float zq1 = acc - cl * (v + mb1[b * 256 + h]) + wd * (u + b1[b * 256 + h]);
    float sg = 1.0f / (1.0f + expf(-zq1));
    ws[OFF_XQ + bl * 256 + h] = zq1 * sg;
}

// ---------------------------------------------------------------------------
// k8: Zq2 -> out[0]. one block per token, 256 threads (d)
// ---------------------------------------------------------------------------
__global__ __launch_bounds__(256) void zq2_kernel(
    const float* __restrict__ b2, const float* __restrict__ mb2,
    float* __restrict__ out, float* __restrict__ ws) {
    int bl = blockIdx.x; int b = bl >> 7; int l = bl & 127;
    int d = threadIdx.x;
    __shared__ float xqs[256];
    __shared__ float ps[128];
    xqs[d] = ws[OFF_XQ + bl * 256 + d];
    if (d < 128) ps[d] = ws[OFF_P2 + bl * Ln + d];
    __syncthreads();
    float acc = 0.0f;
    for (int m = 0; m <= l; ++m)
        acc += ps[m] * ws[OFF_GZ2 + (b * Ln + m) * 256 + d];
    const float* W2t  = ws + OFF_W2T  + b * 65536;
    const float* mW2t = ws + OFF_MW2T + b * 65536;
    float u = 0.0f, v = 0.0f;
#pragma unroll 4
    for (int h = 0; h < 256; ++h) {
        float xh = xqs[h];
        u += xh * W2t[h * 256 + d];
        v += xh * mW2t[h * 256 + d];
    }
    float cl = ws[OFF_C + b * Ln + l];
    float wd = ws[OFF_WDCUM + b * Ln + l];
    out[OUT_ZQ2 + bl * 256 + d] =
        acc - cl * (v + mb2[b * 256 + d]) + wd * (u + b2[b * 256 + d]);
}

// ---------------------------------------------------------------------------
// k9: last-token weight outputs (W1p/mgW1 fam=0, W2p/mgW2 fam=1)
// grid (16,16, B*2); block 256 = 16x16 output tile; inner sum over m=0..127
// ---------------------------------------------------------------------------
__global__ __launch_bounds__(256) void lastw_kernel(
    const float* __restrict__ W1, const float* __restrict__ mW1,
    const float* __restrict__ W2, const float* __restrict__ mW2,
    const float* __restrict__ ws, float* __restrict__ out) {
    int z = blockIdx.z; int b = z >> 1; int fam = z & 1;
    int t = threadIdx.x;
    __shared__ float wa[128], wm[128];
    __shared__ float LA[128][16], LM[128][16], R[128][16];
    const float* lr = ws + OFF_LR + b * Ln;
    const float* Pm = ws + OFF_PM + b * Ln;
    const float* Arow = ws + OFF_A + (b * Ln + Ln - 1) * Ln;
    if (t < 128) {
        wa[t] = Arow[t] * lr[t];
        wm[t] = expf(Pm[Ln - 1] - Pm[t]) * lr[t];
    }
    const float* left  = ws + (fam == 0 ? OFF_GZ1 : OFF_GZ2) + b * Ln * 256;
    const float* right = ws + (fam == 0 ? OFF_K   : OFF_X2 ) + b * Ln * 256;
    int i0 = blockIdx.y * 16, j0 = blockIdx.x * 16;
    __syncthreads();
    for (int e = t; e < 2048; e += 256) {
        int m = e >> 4, i = e & 15;
        float lv = left[m * 256 + i0 + i];
        LA[m][i] = wa[m] * lv;
        LM[m][i] = wm[m] * lv;
        R[m][i]  = right[m * 256 + j0 + i];
    }
    __syncthreads();
    int tx = t & 15, ty = t >> 4;
    float accA = 0.0f, accM = 0.0f;
#pragma unroll 4
    for (int m = 0; m < 128; ++m) {
        accA += LA[m][ty] * R[m][tx];
        accM += LM[m][ty] * R[m][tx];
    }
    float c_last  = ws[OFF_C + b * Ln + Ln - 1];
    float wd_last = ws[OFF_WDCUM + b * Ln + Ln - 1];
    float mc_last = ws[OFF_MOMCUM + b * Ln + Ln - 1];
    int i = i0 + ty, j = j0 + tx;
    const float* base1 = (fam == 0 ? W1 : W2) + b * 65536;
    const float* basem = (fam == 0 ? mW1 : mW2) + b * 65536;
    float b1v = base1[i * 256 + j], bmv = basem[i * 256 + j];
    int op = (fam == 0 ? OUT_W1P : OUT_W2P) + (b * 256 + i) * 256 + j;
    int om = (fam == 0 ? OUT_MGW1 : OUT_MGW2) + (b * 256 + i) * 256 + j;
    out[op] = accA - c_last * bmv + wd_last * b1v;
    out[om] = accM - mc_last * bmv;
}

// ---------------------------------------------------------------------------
// k10: last-token bias outputs. one block per batch, 256 threads
// ---------------------------------------------------------------------------
__global__ __launch_bounds__(256) void lastb_kernel(
    const float* __restrict__ b1, const float* __restrict__ mb1,
    const float* __restrict__ b2, const float* __restrict__ mb2,
    const float* __restrict__ ws, float* __restrict__ out) {
    int b = blockIdx.x; int t = threadIdx.x;
    __shared__ float wa[128], wm[128];
    if (t < 128) {
        wa[t] = ws[OFF_A + (b * Ln + Ln - 1) * Ln + t] * ws[OFF_LR + b * Ln + t];
        wm[t] = expf(ws[OFF_PM + b * Ln + Ln - 1] - ws[OFF_PM + b * Ln + t]) *
                ws[OFF_LR + b * Ln + t];
    }
    __syncthreads();
    const float* gz1 = ws + OFF_GZ1 + b * Ln * 256;
    const float* gz2 = ws + OFF_GZ2 + b * Ln * 256;
    float sA1 = 0, sM1 = 0, sA2 = 0, sM2 = 0;
#pragma unroll 4
    for (int m = 0; m < 128; ++m) {
        float g1 = gz1[m * 256 + t], g2 = gz2[m * 256 + t];
        sA1 += wa[m] * g1; sM1 += wm[m] * g1;
        sA2 += wa[m] * g2; sM2 += wm[m] * g2;
    }
    float c_last  = ws[OFF_C + b * Ln + Ln - 1];
    float wd_last = ws[OFF_WDCUM + b * Ln + Ln - 1];
    float mc_last = ws[OFF_MOMCUM + b * Ln + Ln - 1];
    out[OUT_B1P + b * 256 + t]  = sA1 - c_last * mb1[b * 256 + t] + wd_last * b1[b * 256 + t];
    out[OUT_MGB1 + b * 256 + t] = sM1 - mc_last * mb1[b * 256 + t];
    out[OUT_B2P + b * 256 + t]  = sA2 - c_last * mb2[b * 256 + t] + wd_last * b2[b * 256 + t];
    out[OUT_MGB2 + b * 256 + t] = sM2 - mc_last * mb2[b * 256 + t];
}

// ---------------------------------------------------------------------------
extern "C" void kernel_launch(void* const* d_in, const int* in_sizes, int n_in,
                              void* d_out, int out_size, void* d_ws, size_t ws_size,
                              hipStream_t stream) {
    const float* x   = (const float*)d_in[0];
    const float* Wq  = (const float*)d_in[1];
    const float* bq  = (const float*)d_in[2];
    const float* Wk  = (const float*)d_in[3];
    const float* bk  = (const float*)d_in[4];
    const float* Wv  = (const float*)d_in[5];
    const float* bv  = (const float*)d_in[6];
    const float* Wlr = (const float*)d_in[7];
    const float* blr = (const float*)d_in[8];
    const float* Wm  = (const float*)d_in[9];
    const float* bm  = (const float*)d_in[10];
    const float* Wd  = (const float*)d_in[11];
    const float* bd  = (const float*)d_in[12];
    const float* W1  = (const float*)d_in[13];
    const float* b1  = (const float*)d_in[14];
    const float* W2  = (const float*)d_in[15];
    const float* b2  = (const float*)d_in[16];
    const float* mW1 = (const float*)d_in[17];
    const float* mb1 = (const float*)d_in[18];
    const float* mW2 = (const float*)d_in[19];
    const float* mb2 = (const float*)d_in[20];
    float* ws  = (float*)d_ws;
    float* out = (float*)d_out;

    transpose_kernel<<<dim3(8, 8, 8), 256, 0, stream>>>(W1, W2, mW1, mW2, ws);
    proj_kernel<<<Bn * Ln, 256, 0, stream>>>(x, Wq, bq, Wk, bk, Wv, bv,
                                             Wlr, blr, Wm, bm, Wd, bd, ws);
    scan_kernel<<<Bn, 128, 0, stream>>>(ws);
    a_kernel<<<Bn * Ln, 128, 0, stream>>>(ws);
    fwd_kernel<<<Bn * Ln, 256, 0, stream>>>(W2, b1, b2, ws);
    score_kernel<<<Bn * Ln, 128, 0, stream>>>(ws + OFF_Q, ws + OFF_K, ws + OFF_P1, ws);
    zq1_kernel<<<Bn * Ln, 256, 0, stream>>>(b1, mb1, ws);
    score_kernel<<<Bn * Ln, 128, 0, stream>>>(ws + OFF_XQ, ws + OFF_X2, ws + OFF_P2, ws);
    zq2_kernel<<<Bn * Ln, 256, 0, stream>>>(b2, mb2, out, ws);
    lastw_kernel<<<dim3(16, 16, Bn * 2), 256, 0, stream>>>(W1, mW1, W2, mW2, ws, out);
    lastb_kernel<<<Bn, 256, 0, stream>>>(b1, mb1, b2, mb2, ws, out);
}

// Round 2
// 238.104 us; speedup vs baseline: 1.1501x; 1.1501x over previous
//
#include <hip/hip_runtime.h>
#include <hip/hip_bf16.h>
#include <math.h>

// Problem constants
constexpr int Bn = 2, Ln = 128, Dn = 256, Hn = 256;

// log(expm1(0.01))
#define LR_SHIFT (-4.6001660040607144f)

// Workspace offsets (floats)
constexpr int OFF_Q      = 0;        // [B,L,D]
constexpr int OFF_K      = 65536;    // [B,L,D]
constexpr int OFF_V      = 131072;   // [B,L,D]
constexpr int OFF_X2     = 196608;   // [B,L,H]
constexpr int OFF_GZ1    = 262144;   // [B,L,H]
constexpr int OFF_GZ2    = 327680;   // [B,L,D]
constexpr int OFF_XQ     = 393216;   // [B,L,H]
constexpr int OFF_KT     = 458752;   // [B,256,128]  K transposed (feature-major)
constexpr int OFF_A      = 524288;   // [B,L,L]  A = Dm@M (lower-tri)
constexpr int OFF_W1T    = 557056;   // [B,D,H]  W1 transposed
constexpr int OFF_W2T    = 688128;   // [B,H,D]  W2 transposed
constexpr int OFF_MW1T   = 819200;   // [B,D,H]
constexpr int OFF_MW2T   = 950272;   // [B,H,D]
constexpr int OFF_LR     = 1081344;  // [B,L]
constexpr int OFF_PM     = 1081600;  // [B,L] prefix sum of log_mom (inclusive)
constexpr int OFF_PD     = 1081856;  // [B,L] prefix sum of log_wd
constexpr int OFF_MOMCUM = 1082112;  // [B,L]
constexpr int OFF_WDCUM  = 1082368;  // [B,L]
constexpr int OFF_C      = 1082624;  // [B,L]  c = Dm @ mom_cum
constexpr int OFF_LOGM   = 1082880;  // [B,L]
constexpr int OFF_LOGWD  = 1083136;  // [B,L]
constexpr int OFF_X2T    = 1083392;  // [B,256,128]  X2 transposed
// total 1148928 floats ~= 4.6 MB

// Output offsets (floats), tuple order
constexpr int OUT_ZQ2  = 0;       // [B,L,D]
constexpr int OUT_W1P  = 65536;   // [B,H,D]
constexpr int OUT_B1P  = 196608;  // [B,H]
constexpr int OUT_W2P  = 197120;  // [B,D,H]
constexpr int OUT_B2P  = 328192;  // [B,D]
constexpr int OUT_MGW1 = 328704;  // [B,H,D]
constexpr int OUT_MGB1 = 459776;  // [B,H]
constexpr int OUT_MGW2 = 460288;  // [B,D,H]
constexpr int OUT_MGB2 = 591360;  // [B,D]

__device__ __forceinline__ float softplus_f(float z) {
    return fmaxf(z, 0.0f) + log1pf(expf(-fabsf(z)));
}

__device__ __forceinline__ float4 fma4(float s, const float4 w, float4 a) {
    a.x += s * w.x; a.y += s * w.y; a.z += s * w.z; a.w += s * w.w; return a;
}

// ---------------------------------------------------------------------------
// k0: transpose W1, W2, mW1, mW2 (each [256,256] per batch) into workspace
// ---------------------------------------------------------------------------
__global__ __launch_bounds__(256) void transpose_kernel(
    const float* __restrict__ W1, const float* __restrict__ W2,
    const float* __restrict__ mW1, const float* __restrict__ mW2,
    float* __restrict__ ws) {
    int z = blockIdx.z; int mat = z >> 1; int b = z & 1;
    const float* src; float* dst;
    if (mat == 0)      { src = W1  + b * 65536; dst = ws + OFF_W1T  + b * 65536; }
    else if (mat == 1) { src = W2  + b * 65536; dst = ws + OFF_W2T  + b * 65536; }
    else if (mat == 2) { src = mW1 + b * 65536; dst = ws + OFF_MW1T + b * 65536; }
    else               { src = mW2 + b * 65536; dst = ws + OFF_MW2T + b * 65536; }
    __shared__ float tile[32][33];
    int tx = threadIdx.x & 31, ty = threadIdx.x >> 5;
    int r0 = blockIdx.y * 32, c0 = blockIdx.x * 32;
    for (int i = 0; i < 32; i += 8)
        tile[ty + i][tx] = src[(r0 + ty + i) * 256 + (c0 + tx)];
    __syncthreads();
    for (int i = 0; i < 32; i += 8)
        dst[(c0 + ty + i) * 256 + (r0 + tx)] = tile[tx][ty + i];
}

// ---------------------------------------------------------------------------
// k1: Q/K/V projections + scalar projections. Split-K float4 matvecs.
// one block per token (b,l); 256 threads as (o = t&63 output-quad, dl = t>>6)
// ---------------------------------------------------------------------------
__global__ __launch_bounds__(256) void proj_kernel(
    const float* __restrict__ x,
    const float* __restrict__ Wq, const float* __restrict__ bq,
    const float* __restrict__ Wk, const float* __restrict__ bk,
    const float* __restrict__ Wv, const float* __restrict__ bv,
    const float* __restrict__ Wlr, const float* __restrict__ blr,
    const float* __restrict__ Wm, const float* __restrict__ bm,
    const float* __restrict__ Wd, const float* __restrict__ bd,
    float* __restrict__ ws) {
    int bl = blockIdx.x;
    int t = threadIdx.x;
    int o = t & 63, dl = t >> 6;
    __shared__ float xs[256];
    __shared__ float rq[1024], rk[1024], rv[1024];
    xs[t] = x[bl * 256 + t];
    __syncthreads();

    float4 aq = {0, 0, 0, 0}, ak = {0, 0, 0, 0}, av = {0, 0, 0, 0};
#pragma unroll 4
    for (int i = 0; i < 64; ++i) {
        int d = dl + 4 * i;
        float xv = xs[d];
        aq = fma4(xv, *(const float4*)(Wq + d * 256 + 4 * o), aq);
        ak = fma4(xv, *(const float4*)(Wk + d * 256 + 4 * o), ak);
        av = fma4(xv, *(const float4*)(Wv + d * 256 + 4 * o), av);
    }
    *(float4*)(rq + dl * 256 + 4 * o) = aq;
    *(float4*)(rk + dl * 256 + 4 * o) = ak;
    *(float4*)(rv + dl * 256 + 4 * o) = av;
    __syncthreads();
    float q = rq[t] + rq[256 + t] + rq[512 + t] + rq[768 + t] + bq[t];
    float k = rk[t] + rk[256 + t] + rk[512 + t] + rk[768 + t] + bk[t];
    float v = rv[t] + rv[256 + t] + rv[512 + t] + rv[768 + t] + bv[t];
    ws[OFF_Q + bl * 256 + t] = q;
    ws[OFF_K + bl * 256 + t] = k;
    ws[OFF_V + bl * 256 + t] = v;
    __syncthreads();  // all reads of rq/rk/rv done before reuse

    // three scalar dot products over D
    rq[t] = xs[t] * Wlr[t];
    rk[t] = xs[t] * Wm[t];
    rv[t] = xs[t] * Wd[t];
    __syncthreads();
    for (int s = 128; s > 0; s >>= 1) {
        if (t < s) { rq[t] += rq[t + s]; rk[t] += rk[t + s]; rv[t] += rv[t + s]; }
        __syncthreads();
    }
    if (t == 0) {
        ws[OFF_LR + bl]    = softplus_f(rq[0] + blr[0] + LR_SHIFT);
        ws[OFF_LOGM + bl]  = -softplus_f(-(rk[0] + bm[0]));
        ws[OFF_LOGWD + bl] = -softplus_f(rv[0] + bd[0]);
    }
}

// ---------------------------------------------------------------------------
// k2: per-batch prefix scans -> Pm, Pd, mom_cum, wd_cum, c
// ---------------------------------------------------------------------------
__global__ __launch_bounds__(128) void scan_kernel(float* __restrict__ ws) {
    int b = blockIdx.x; int t = threadIdx.x;
    __shared__ float sm[128], sd[128], se[128];
    sm[t] = ws[OFF_LOGM + b * Ln + t];
    sd[t] = ws[OFF_LOGWD + b * Ln + t];
    __syncthreads();
    for (int off = 1; off < 128; off <<= 1) {
        float am = (t >= off) ? sm[t - off] : 0.0f;
        float ad = (t >= off) ? sd[t - off] : 0.0f;
        __syncthreads();
        sm[t] += am; sd[t] += ad;
        __syncthreads();
    }
    float pm = sm[t], pd = sd[t];
    ws[OFF_PM + b * Ln + t] = pm;
    ws[OFF_PD + b * Ln + t] = pd;
    ws[OFF_MOMCUM + b * Ln + t] = expf(pm);
    ws[OFF_WDCUM + b * Ln + t]  = expf(pd);
    se[t] = expf(pm - pd);
    __syncthreads();
    for (int off = 1; off < 128; off <<= 1) {
        float a = (t >= off) ? se[t - off] : 0.0f;
        __syncthreads();
        se[t] += a;
        __syncthreads();
    }
    ws[OFF_C + b * Ln + t] = expf(pd) * se[t];
}

// ---------------------------------------------------------------------------
// k3: A = Dm @ M  (lower-tri, per batch)
// ---------------------------------------------------------------------------
__global__ __launch_bounds__(128) void a_kernel(float* __restrict__ ws) {
    int bl = blockIdx.x; int b = bl >> 7; int l = bl & 127;
    int m1 = threadIdx.x;
    const float* Pm = ws + OFF_PM + b * Ln;
    const float* Pd = ws + OFF_PD + b * Ln;
    float a = 0.0f;
    if (m1 <= l) {
        float pdl = Pd[l], pmm1 = Pm[m1];
        float s = 0.0f;
        for (int m = m1; m <= l; ++m)
            s += expf((pdl - Pd[m]) + (Pm[m] - pmm1));
        a = s;
    }
    ws[OFF_A + bl * Ln + m1] = a;
}

// ---------------------------------------------------------------------------
// k4: forward MLP + per-token grads. Split-K float4 matvecs.
// ---------------------------------------------------------------------------
__global__ __launch_bounds__(256) void fwd_kernel(
    const float* __restrict__ W2g, const float* __restrict__ b1,
    const float* __restrict__ b2, float* __restrict__ ws) {
    int bl = blockIdx.x, b = bl >> 7, t = threadIdx.x;
    int o = t & 63, dl = t >> 6;
    __shared__ float ks[256], x2s[256], gz2s[256], red[1024];
    const float* W1t = ws + OFF_W1T + b * 65536;
    const float* W2t = ws + OFF_W2T + b * 65536;
    const float* W2n = W2g + b * 65536;
    ks[t] = ws[OFF_K + bl * 256 + t];
    __syncthreads();

    // Z1[h] = b1 + sum_d W1t[d][h] * k[d]
    float4 a1 = {0, 0, 0, 0};
#pragma unroll 8
    for (int i = 0; i < 64; ++i) {
        int d = dl + 4 * i;
        a1 = fma4(ks[d], *(const float4*)(W1t + d * 256 + 4 * o), a1);
    }
    *(float4*)(red + dl * 256 + 4 * o) = a1;
    __syncthreads();
    float z1 = red[t] + red[256 + t] + red[512 + t] + red[768 + t] + b1[b * 256 + t];
    float sg = 1.0f / (1.0f + expf(-z1));
    float x2 = z1 * sg;
    ws[OFF_X2 + bl * 256 + t] = x2;
    x2s[t] = x2;
    __syncthreads();

    // Z2[d] = b2 + sum_h W2t[h][d] * x2[h]
    float4 a2 = {0, 0, 0, 0};
#pragma unroll 8
    for (int i = 0; i < 64; ++i) {
        int h = dl + 4 * i;
        a2 = fma4(x2s[h], *(const float4*)(W2t + h * 256 + 4 * o), a2);
    }
    *(float4*)(red + dl * 256 + 4 * o) = a2;
    __syncthreads();
    float z2 = red[t] + red[256 + t] + red[512 + t] + red[768 + t] + b2[b * 256 + t];
    float gz2 = z2 - ws[OFF_V + bl * 256 + t];
    ws[OFF_GZ2 + bl * 256 + t] = gz2;
    gz2s[t] = gz2;
    __syncthreads();

    // gX2[h] = sum_d gz2[d] * W2[d][h]  (native layout)
    float4 a3 = {0, 0, 0, 0};
#pragma unroll 8
    for (int i = 0; i < 64; ++i) {
        int d = dl + 4 * i;
        a3 = fma4(gz2s[d], *(const float4*)(W2n + d * 256 + 4 * o), a3);
    }
    *(float4*)(red + dl * 256 + 4 * o) = a3;
    __syncthreads();
    float gx2 = red[t] + red[256 + t] + red[512 + t] + red[768 + t];
    float gz1 = gx2 * (x2 + sg * (1.0f - x2));
    ws[OFF_GZ1 + bl * 256 + t] = gz1;
}

// ---------------------------------------------------------------------------
// k5: transpose K and X2 ([B,128,256] -> [B,256,128]) for coalesced scores
// grid (8 n-tiles, 4 l-tiles, 4 = b + 2*mat)
// ---------------------------------------------------------------------------
__global__ __launch_bounds__(256) void transpkx_kernel(float* __restrict__ ws) {
    int z = blockIdx.z; int b = z & 1; int mat = z >> 1;
    const float* src = ws + (mat ? OFF_X2 : OFF_K) + b * 32768;
    float* dst = ws + (mat ? OFF_X2T : OFF_KT) + b * 32768;
    __shared__ float tile[32][33];
    int tx = threadIdx.x & 31, ty = threadIdx.x >> 5;
    int l0 = blockIdx.y * 32, n0 = blockIdx.x * 32;
    for (int i = 0; i < 32; i += 8)
        tile[ty + i][tx] = src[(l0 + ty + i) * 256 + (n0 + tx)];
    __syncthreads();
    for (int i = 0; i < 32; i += 8)
        dst[(n0 + ty + i) * 128 + (l0 + tx)] = tile[tx][ty + i];
}

// ---------------------------------------------------------------------------
// k6: fused score1 + Zq1 + silu -> XQ. one block per token.
// ---------------------------------------------------------------------------
__global__ __launch_bounds__(256) void zq1_kernel(
    const float* __restrict__ b1, const float* __restrict__ mb1,
    float* __restrict__ ws) {
    int bl = blockIdx.x, b = bl >> 7, l = bl & 127, t = threadIdx.x;
    int o = t & 63, dl = t >> 6, m4 = t & 31, sl = t >> 5;
    __shared__ float qs[256], ps[128], red[1024], ru[1024], rv[1024];
    qs[t] = ws[OFF_Q + bl * 256 + t];
    __syncthreads();

    // scores: s[m] = q . k[m]  via Kt (feature-major), 8-way split-K
    const float* Kt = ws + OFF_KT + b * 32768;
    float4 as = {0, 0, 0, 0};
#pragma unroll 8
    for (int i = 0; i < 32; ++i) {
        int d = sl + 8 * i;
        as = fma4(qs[d], *(const float4*)(Kt + d * 128 + 4 * m4), as);
    }
    *(float4*)(red + sl * 128 + 4 * m4) = as;
    __syncthreads();
    if (t < 128) {
        float s = 0.0f;
#pragma unroll
        for (int j = 0; j < 8; ++j) s += red[j * 128 + t];
        float p = 0.0f;
        if (t <= l)
            p = ws[OFF_A + bl * Ln + t] * ws[OFF_LR + b * Ln + t] * (1.0f + s);
        ps[t] = p;
    }
    __syncthreads();

    // u = W1 q, v = mW1 q (via transposed layouts)
    const float* W1t  = ws + OFF_W1T  + b * 65536;
    const float* mW1t = ws + OFF_MW1T + b * 65536;
    float4 au = {0, 0, 0, 0}, av = {0, 0, 0, 0};
#pragma unroll 4
    for (int i = 0; i < 64; ++i) {
        int d = dl + 4 * i;
        float qd = qs[d];
        au = fma4(qd, *(const float4*)(W1t  + d * 256 + 4 * o), au);
        av = fma4(qd, *(const float4*)(mW1t + d * 256 + 4 * o), av);
    }
    *(float4*)(ru + dl * 256 + 4 * o) = au;
    *(float4*)(rv + dl * 256 + 4 * o) = av;

    // P-contraction: sum_{m<=l} ps[m]*gZ1[m][h]
    const float* gz1p = ws + OFF_GZ1 + b * 32768;
    float accp = 0.0f;
#pragma unroll 4
    for (int m = 0; m <= l; ++m) accp += ps[m] * gz1p[m * 256 + t];
    __syncthreads();
    float u = ru[t] + ru[256 + t] + ru[512 + t] + ru[768 + t];
    float v = rv[t] + rv[256 + t] + rv[512 + t] + rv[768 + t];
    float cl = ws[OFF_C + b * Ln + l];
    float wd = ws[OFF_WDCUM + b * Ln + l];
    float z = accp - cl * (v + mb1[b * 256 + t]) + wd * (u + b1[b * 256 + t]);
    float sg = 1.0f / (1.0f + expf(-z));
    ws[OFF_XQ + bl * 256 + t] = z * sg;
}

// ---------------------------------------------------------------------------
// k7: fused score2 + Zq2 -> out. one block per token.
// ---------------------------------------------------------------------------
__global__ __launch_bounds__(256) void zq2_kernel(
    const float* __restrict__ b2, const float* __restrict__ mb2,
    float* __restrict__ out, float* __restrict__ ws) {
    int bl = blockIdx.x, b = bl >> 7, l = bl & 127, t = threadIdx.x;
    int o = t & 63, dl = t >> 6, m4 = t & 31, sl = t >> 5;
    __shared__ float xqs[256], ps[128], red[1024], ru[1024], rv[1024];
    xqs[t] = ws[OFF_XQ + bl * 256 + t];
    __syncthreads();

    const float* X2t = ws + OFF_X2T + b * 32768;
    float4 as = {0, 0, 0, 0};
#pragma unroll 8
    for (int i = 0; i < 32; ++i) {
        int h = sl + 8 * i;
        as = fma4(xqs[h], *(const float4*)(X2t + h * 128 + 4 * m4), as);
    }
    *(float4*)(red + sl * 128 + 4 * m4) = as;
    __syncthreads();
    if (t < 128) {
        float s = 0.0f;
#pragma unroll
        for (int j = 0; j < 8; ++j) s += red[j * 128 + t];
        float p = 0.0f;
        if (t <= l)
            p = ws[OFF_A + bl * Ln + t] * ws[OFF_LR + b * Ln + t] * (1.0f + s);
        ps[t] = p;
    }
    __syncthreads();

    const float* W2t  = ws + OFF_W2T  + b * 65536;
    const float* mW2t = ws + OFF_MW2T + b * 65536;
    float4 au = {0, 0, 0, 0}, av = {0, 0, 0, 0};
#pragma unroll 4
    for (int i = 0; i < 64; ++i) {
        int h = dl + 4 * i;
        float xh = xqs[h];
        au = fma4(xh, *(const float4*)(W2t  + h * 256 + 4 * o), au);
        av = fma4(xh, *(const float4*)(mW2t + h * 256 + 4 * o), av);
    }
    *(float4*)(ru + dl * 256 + 4 * o) = au;
    *(float4*)(rv + dl * 256 + 4 * o) = av;

    const float* gz2p = ws + OFF_GZ2 + b * 32768;
    float accp = 0.0f;
#pragma unroll 4
    for (int m = 0; m <= l; ++m) accp += ps[m] * gz2p[m * 256 + t];
    __syncthreads();
    float u = ru[t] + ru[256 + t] + ru[512 + t] + ru[768 + t];
    float v = rv[t] + rv[256 + t] + rv[512 + t] + rv[768 + t];
    float cl = ws[OFF_C + b * Ln + l];
    float wd = ws[OFF_WDCUM + b * Ln + l];
    out[OUT_ZQ2 + bl * 256 + t] =
        accp - cl * (v + mb2[b * 256 + t]) + wd * (u + b2[b * 256 + t]);
}

// ---------------------------------------------------------------------------
// k8: last-token weight outputs (W1p/mgW1 fam=0, W2p/mgW2 fam=1)
// ---------------------------------------------------------------------------
__global__ __launch_bounds__(256) void lastw_kernel(
    const float* __restrict__ W1, const float* __restrict__ mW1,
    const float* __restrict__ W2, const float* __restrict__ mW2,
    const float* __restrict__ ws, float* __restrict__ out) {
    int z = blockIdx.z; int b = z >> 1; int fam = z & 1;
    int t = threadIdx.x;
    __shared__ float wa[128], wm[128];
    __shared__ float LA[128][16], LM[128][16], R[128][16];
    const float* lr = ws + OFF_LR + b * Ln;
    const float* Pm = ws + OFF_PM + b * Ln;
    const float* Arow = ws + OFF_A + (b * Ln + Ln - 1) * Ln;
    if (t < 128) {
        wa[t] = Arow[t] * lr[t];
        wm[t] = expf(Pm[Ln - 1] - Pm[t]) * lr[t];
    }
    const float* left  = ws + (fam == 0 ? OFF_GZ1 : OFF_GZ2) + b * Ln * 256;
    const float* right = ws + (fam == 0 ? OFF_K   : OFF_X2 ) + b * Ln * 256;
    int i0 = blockIdx.y * 16, j0 = blockIdx.x * 16;
    __syncthreads();
    for (int e = t; e < 2048; e += 256) {
        int m = e >> 4, i = e & 15;
        float lv = left[m * 256 + i0 + i];
        LA[m][i] = wa[m] * lv;
        LM[m][i] = wm[m] * lv;
        R[m][i]  = right[m * 256 + j0 + i];
    }
    __syncthreads();
    int tx = t & 15, ty = t >> 4;
    float accA = 0.0f, accM = 0.0f;
#pragma unroll 4
    for (int m = 0; m < 128; ++m) {
        accA += LA[m][ty] * R[m][tx];
        accM += LM[m][ty] * R[m][tx];
    }
    float c_last  = ws[OFF_C + b * Ln + Ln - 1];
    float wd_last = ws[OFF_WDCUM + b * Ln + Ln - 1];
    float mc_last = ws[OFF_MOMCUM + b * Ln + Ln - 1];
    int i = i0 + ty, j = j0 + tx;
    const float* base1 = (fam == 0 ? W1 : W2) + b * 65536;
    const float* basem = (fam == 0 ? mW1 : mW2) + b * 65536;
    float b1v = base1[i * 256 + j], bmv = basem[i * 256 + j];
    int op = (fam == 0 ? OUT_W1P : OUT_W2P) + (b * 256 + i) * 256 + j;
    int om = (fam == 0 ? OUT_MGW1 : OUT_MGW2) + (b * 256 + i) * 256 + j;
    out[op] = accA - c_last * bmv + wd_last * b1v;
    out[om] = accM - mc_last * bmv;
}

// ---------------------------------------------------------------------------
// k9: last-token bias outputs
// ---------------------------------------------------------------------------
__global__ __launch_bounds__(256) void lastb_kernel(
    const float* __restrict__ b1, const float* __restrict__ mb1,
    const float* __restrict__ b2, const float* __restrict__ mb2,
    const float* __restrict__ ws, float* __restrict__ out) {
    int b = blockIdx.x; int t = threadIdx.x;
    __shared__ float wa[128], wm[128];
    if (t < 128) {
        wa[t] = ws[OFF_A + (b * Ln + Ln - 1) * Ln + t] * ws[OFF_LR + b * Ln + t];
        wm[t] = expf(ws[OFF_PM + b * Ln + Ln - 1] - ws[OFF_PM + b * Ln + t]) *
                ws[OFF_LR + b * Ln + t];
    }
    __syncthreads();
    const float* gz1 = ws + OFF_GZ1 + b * Ln * 256;
    const float* gz2 = ws + OFF_GZ2 + b * Ln * 256;
    float sA1 = 0, sM1 = 0, sA2 = 0, sM2 = 0;
#pragma unroll 4
    for (int m = 0; m < 128; ++m) {
        float g1 = gz1[m * 256 + t], g2 = gz2[m * 256 + t];
        sA1 += wa[m] * g1; sM1 += wm[m] * g1;
        sA2 += wa[m] * g2; sM2 += wm[m] * g2;
    }
    float c_last  = ws[OFF_C + b * Ln + Ln - 1];
    float wd_last = ws[OFF_WDCUM + b * Ln + Ln - 1];
    float mc_last = ws[OFF_MOMCUM + b * Ln + Ln - 1];
    out[OUT_B1P + b * 256 + t]  = sA1 - c_last * mb1[b * 256 + t] + wd_last * b1[b * 256 + t];
    out[OUT_MGB1 + b * 256 + t] = sM1 - mc_last * mb1[b * 256 + t];
    out[OUT_B2P + b * 256 + t]  = sA2 - c_last * mb2[b * 256 + t] + wd_last * b2[b * 256 + t];
    out[OUT_MGB2 + b * 256 + t] = sM2 - mc_last * mb2[b * 256 + t];
}

// ---------------------------------------------------------------------------
extern "C" void kernel_launch(void* const* d_in, const int* in_sizes, int n_in,
                              void* d_out, int out_size, void* d_ws, size_t ws_size,
                              hipStream_t stream) {
    const float* x   = (const float*)d_in[0];
    const float* Wq  = (const float*)d_in[1];
    const float* bq  = (const float*)d_in[2];
    const float* Wk  = (const float*)d_in[3];
    const float* bk  = (const float*)d_in[4];
    const float* Wv  = (const float*)d_in[5];
    const float* bv  = (const float*)d_in[6];
    const float* Wlr = (const float*)d_in[7];
    const float* blr = (const float*)d_in[8];
    const float* Wm  = (const float*)d_in[9];
    const float* bm  = (const float*)d_in[10];
    const float* Wd  = (const float*)d_in[11];
    const float* bd  = (const float*)d_in[12];
    const float* W1  = (const float*)d_in[13];
    const float* b1  = (const float*)d_in[14];
    const float* W2  = (const float*)d_in[15];
    const float* b2  = (const float*)d_in[16];
    const float* mW1 = (const float*)d_in[17];
    const float* mb1 = (const float*)d_in[18];
    const float* mW2 = (const float*)d_in[19];
    const float* mb2 = (const float*)d_in[20];
    float* ws  = (float*)d_ws;
    float* out = (float*)d_out;

    transpose_kernel<<<dim3(8, 8, 8), 256, 0, stream>>>(W1, W2, mW1, mW2, ws);
    proj_kernel<<<Bn * Ln, 256, 0, stream>>>(x, Wq, bq, Wk, bk, Wv, bv,
                                             Wlr, blr, Wm, bm, Wd, bd, ws);
    scan_kernel<<<Bn, 128, 0, stream>>>(ws);
    a_kernel<<<Bn * Ln, 128, 0, stream>>>(ws);
    fwd_kernel<<<Bn * Ln, 256, 0, stream>>>(W2, b1, b2, ws);
    transpkx_kernel<<<dim3(8, 4, 4), 256, 0, stream>>>(ws);
    zq1_kernel<<<Bn * Ln, 256, 0, stream>>>(b1, mb1, ws);
    zq2_kernel<<<Bn * Ln, 256, 0, stream>>>(b2, mb2, out, ws);
    lastw_kernel<<<dim3(16, 16, Bn * 2), 256, 0, stream>>>(W1, mW1, W2, mW2, ws, out);
    lastb_kernel<<<Bn, 256, 0, stream>>>(b1, mb1, b2, mb2, ws, out);
}